// Round 4
// baseline (458.932 us; speedup 1.0000x reference)
//
#include <hip/hip_runtime.h>
#include <hip/hip_bf16.h>

// Problem constants (B=32, N=256, K=8, D=1024, OUT=1024, HID=2048)
#define ROWS   8192      // B*N
#define DIM    1024      // D
#define XCOLS  3072      // 3*D
#define OUTC   1024
#define HIDC   2048
#define EPS    1e-5f

typedef __attribute__((ext_vector_type(8))) short bf16x8;    // 8 bf16 (4 VGPRs)
typedef __attribute__((ext_vector_type(4))) float f32x4;
typedef __attribute__((ext_vector_type(16))) float f32x16;   // 32x32 MFMA acc

#define GLOBAL_AS __attribute__((address_space(1)))
#define LDS_AS    __attribute__((address_space(3)))

__device__ __forceinline__ void gll16(const void* g, void* l) {
    // async global->LDS, 16B per lane; LDS dest = wave-uniform base + lane*16
    __builtin_amdgcn_global_load_lds((const GLOBAL_AS void*)g, (LDS_AS void*)l, 16, 0, 0);
}

__device__ __forceinline__ short f2b(float f) {
    __hip_bfloat16 h = __float2bfloat16(f);
    return *reinterpret_cast<short*>(&h);
}
__device__ __forceinline__ float b2f(short s) {
    unsigned u = ((unsigned)(unsigned short)s) << 16;
    return __uint_as_float(u);
}

// ---------------------------------------------------------------------------
// Stage 1: x[r, 0:1024] = self[r, :]; x[r, 1024:3072] = mean_k(nb[r,k,:]*mask[r,k])
// ---------------------------------------------------------------------------
__global__ __launch_bounds__(256) void build_x(
    const float* __restrict__ selfv, const float* __restrict__ nb,
    const float* __restrict__ mask, __hip_bfloat16* __restrict__ xb)
{
    int r = blockIdx.x;
    int tid = threadIdx.x;
    __shared__ float ms[8];
    if (tid < 8) ms[tid] = mask[r * 8 + tid];
    __syncthreads();

    __hip_bfloat16* xr = xb + (size_t)r * XCOLS;

    // self part: 1024 floats = 256 float4, one per thread
    {
        float4 v = ((const float4*)(selfv + (size_t)r * DIM))[tid];
        short4 o;
        o.x = f2b(v.x); o.y = f2b(v.y); o.z = f2b(v.z); o.w = f2b(v.w);
        *(short4*)&xr[tid * 4] = o;
    }

    // entity part: 2048 cols, masked mean over K=8
    const float4* nbase = (const float4*)(nb + (size_t)r * 8 * 2048);
#pragma unroll
    for (int half = 0; half < 2; ++half) {
        int c4 = half * 256 + tid;            // float4 index in [0,512)
        float4 acc = make_float4(0.f, 0.f, 0.f, 0.f);
#pragma unroll
        for (int k = 0; k < 8; ++k) {
            float4 t = nbase[k * 512 + c4];
            float m = ms[k];
            acc.x += t.x * m; acc.y += t.y * m; acc.z += t.z * m; acc.w += t.w * m;
        }
        short4 o;
        o.x = f2b(acc.x * 0.125f); o.y = f2b(acc.y * 0.125f);
        o.z = f2b(acc.z * 0.125f); o.w = f2b(acc.w * 0.125f);
        *(short4*)&xr[1024 + c4 * 4] = o;
    }
}

// ---------------------------------------------------------------------------
// Weight transpose + bf16 cast: W[K][N] f32 -> Wt[N][K] bf16
// ---------------------------------------------------------------------------
__global__ __launch_bounds__(256) void wtrans(
    const float* __restrict__ W, __hip_bfloat16* __restrict__ Wt, int K, int N)
{
    __shared__ float t[32][33];
    int n0 = blockIdx.x << 5, k0 = blockIdx.y << 5;
    int tx = threadIdx.x & 31, ty = threadIdx.x >> 5;   // 32 x 8
#pragma unroll
    for (int i = 0; i < 4; ++i)
        t[ty + i * 8][tx] = W[(size_t)(k0 + ty + i * 8) * N + n0 + tx];
    __syncthreads();
#pragma unroll
    for (int i = 0; i < 4; ++i) {
        int n = ty + i * 8;
        Wt[(size_t)(n0 + n) * K + k0 + tx] = __float2bfloat16(t[tx][n]);
    }
}

// ---------------------------------------------------------------------------
// GEMM: C[M,N] = A[M,K] @ Bt[N,K]^T + bias   (bf16 in, f32 acc)
// 128x128 tile, BK=32, 4 waves (2x2), 32x32x16 MFMA (2x2 frags per wave),
// 2-phase double-buffered LDS (STAGE(t+1) before compute(t), one barrier/iter).
// OUT_BF16: 1 -> bf16 C, 0 -> f32 C.
// STATS:    1 -> per-block-row column partials (sum, sumsq) incl. bias
//                into pS/pS2[bm * N + col]  (deterministic, for BatchNorm)
// ---------------------------------------------------------------------------
template <int OUT_BF16, int STATS>
__global__ __launch_bounds__(256) void gemm_bt(
    const short* __restrict__ A, const short* __restrict__ Bt,
    const float* __restrict__ bias, void* __restrict__ Cout,
    float* __restrict__ pS, float* __restrict__ pS2,
    int M, int N, int K)
{
    __shared__ short As[2][128 * 32];
    __shared__ short Bs[2][128 * 32];

    int tid = threadIdx.x;
    int lane = tid & 63;
    int w = tid >> 6;
    int wm = w >> 1, wn = w & 1;

    // XCD swizzle: contiguous chunk of blocks per XCD (T1; grid %8==0)
    int nwg = gridDim.x;
    int bid = blockIdx.x;
    int swz = (bid & 7) * (nwg >> 3) + (bid >> 3);

    int nbn = N >> 7;
    int bm = swz / nbn, bn = swz % nbn;
    int brow = bm << 7, bcol = bn << 7;

    f32x16 acc[2][2] = {};

    // staging addresses: slot s covers row s/4, col-elems (s%4)*8 of the 128x32 tile
    int s0 = tid, s1 = tid + 256;
    const short* gA0 = A + (size_t)(brow + (s0 >> 2)) * K + ((s0 & 3) << 3);
    const short* gA1 = A + (size_t)(brow + (s1 >> 2)) * K + ((s1 & 3) << 3);
    const short* gB0 = Bt + (size_t)(bcol + (s0 >> 2)) * K + ((s0 & 3) << 3);
    const short* gB1 = Bt + (size_t)(bcol + (s1 >> 2)) * K + ((s1 & 3) << 3);
    int lofs = w << 9;                 // wave's slot region (w*64 slots * 8 elems)

    // 32x32x16 operand addressing: lane holds row=lane&31, k=(lane>>5)*8..+7
    int rowa32 = (wm << 6) + (lane & 31);
    int rowb32 = (wn << 6) + (lane & 31);
    int kc32 = (lane >> 5) << 3;       // 0 or 8 within a K=16 sub-step

#define STAGE(buf, kk)                                  \
    do {                                                \
        gll16(gA0 + (kk), &As[buf][lofs]);              \
        gll16(gA1 + (kk), &As[buf][2048 + lofs]);       \
        gll16(gB0 + (kk), &Bs[buf][lofs]);              \
        gll16(gB1 + (kk), &Bs[buf][2048 + lofs]);       \
    } while (0)

    int nk = K >> 5;
    STAGE(0, 0);
    __syncthreads();                   // implicit vmcnt(0) drain -> tile 0 valid

    int cur = 0;
    for (int i = 0; i < nk; ++i) {
        if (i + 1 < nk) STAGE(cur ^ 1, (i + 1) << 5);   // prefetch next tile

        bf16x8 a[2][2], b[2][2];       // [frag][k-sub]
#pragma unroll
        for (int m = 0; m < 2; ++m)
#pragma unroll
            for (int ks = 0; ks < 2; ++ks)
                a[m][ks] = *(const bf16x8*)
                    &As[cur][((rowa32 + (m << 5)) << 5) + (ks << 4) + kc32];
#pragma unroll
        for (int n = 0; n < 2; ++n)
#pragma unroll
            for (int ks = 0; ks < 2; ++ks)
                b[n][ks] = *(const bf16x8*)
                    &Bs[cur][((rowb32 + (n << 5)) << 5) + (ks << 4) + kc32];

#pragma unroll
        for (int m = 0; m < 2; ++m)
#pragma unroll
            for (int n = 0; n < 2; ++n) {
                acc[m][n] = __builtin_amdgcn_mfma_f32_32x32x16_bf16(
                    a[m][0], b[n][0], acc[m][n], 0, 0, 0);
                acc[m][n] = __builtin_amdgcn_mfma_f32_32x32x16_bf16(
                    a[m][1], b[n][1], acc[m][n], 0, 0, 0);
            }

        __syncthreads();   // drains prefetch (after compute) + LDS reuse fence
        cur ^= 1;
    }
#undef STAGE

    // epilogue: 32x32 C/D layout col=lane&31, row=(reg&3)+8*(reg>>2)+4*(lane>>5)
    int rbase = brow + (wm << 6) + ((lane >> 5) << 2);
    int ccol0 = bcol + (wn << 6) + (lane & 31);
    float cs[2] = {0.f, 0.f}, cs2[2] = {0.f, 0.f};
#pragma unroll
    for (int m = 0; m < 2; ++m) {
#pragma unroll
        for (int n = 0; n < 2; ++n) {
            int col = ccol0 + (n << 5);
            float bv = bias[col];
#pragma unroll
            for (int reg = 0; reg < 16; ++reg) {
                int row = rbase + (m << 5) + (reg & 3) + ((reg >> 2) << 3);
                float v = acc[m][n][reg] + bv;
                if (OUT_BF16) {
                    ((__hip_bfloat16*)Cout)[(size_t)row * N + col] = __float2bfloat16(v);
                } else {
                    ((float*)Cout)[(size_t)row * N + col] = v;
                }
                if (STATS) { cs[n] += v; cs2[n] += v * v; }
            }
        }
    }

    if (STATS) {
        // lanes l and l^32 share a column (hi bit selects row offset 4):
        // one xor-32 completes the column sum over this wave's 64 rows.
        float* sP = (float*)&As[0][0];   // reuse LDS (fenced by loop barrier)
#pragma unroll
        for (int n = 0; n < 2; ++n) {
            float s = cs[n], s2 = cs2[n];
            s  += __shfl_xor(s, 32);
            s2 += __shfl_xor(s2, 32);
            if ((lane >> 5) == 0) {
                int c = (wn << 6) + (n << 5) + (lane & 31);
                sP[wm * 128 + c] = s;
                sP[256 + wm * 128 + c] = s2;
            }
        }
        __syncthreads();
        if (tid < 128) {
            float s = sP[tid] + sP[128 + tid];
            float s2 = sP[256 + tid] + sP[384 + tid];
            pS [(size_t)bm * N + bcol + tid] = s;
            pS2[(size_t)bm * N + bcol + tid] = s2;
        }
    }
}

// ---------------------------------------------------------------------------
// BN stats reduce: 64 row-chunk partials -> per-column scale/shift
// ---------------------------------------------------------------------------
__global__ __launch_bounds__(256) void bn_stats2(
    const float* __restrict__ pS, const float* __restrict__ pS2,
    const float* __restrict__ g, const float* __restrict__ be,
    float* __restrict__ scale, float* __restrict__ shift, int ncols)
{
    int col = blockIdx.x * 256 + threadIdx.x;
    float s = 0.f, s2 = 0.f;
#pragma unroll
    for (int j = 0; j < 64; ++j) {
        s += pS[j * ncols + col];
        s2 += pS2[j * ncols + col];
    }
    float mu = s * (1.f / 8192.f);
    float var = s2 * (1.f / 8192.f) - mu * mu;
    float rs = rsqrtf(var + EPS);
    float sc = g[col] * rs;
    scale[col] = sc;
    shift[col] = be[col] - mu * sc;
}

// BN apply + ReLU, bf16 in -> bf16 out (hidden activation)
__global__ __launch_bounds__(256) void bn_apply_b2b(
    const short* __restrict__ t, const float* __restrict__ scale,
    const float* __restrict__ shift, short* __restrict__ out, int ncols)
{
    size_t i8 = (size_t)blockIdx.x * 256 + threadIdx.x;
    int col0 = (int)((i8 * 8) % ncols);
    bf16x8 v = ((const bf16x8*)t)[i8];
    bf16x8 o;
#pragma unroll
    for (int j = 0; j < 8; ++j) {
        float f = fmaxf(b2f(v[j]) * scale[col0 + j] + shift[col0 + j], 0.f);
        o[j] = f2b(f);
    }
    ((bf16x8*)out)[i8] = o;
}

// BN apply + ReLU, f32 in -> f32 out (final, in-place on d_out)
__global__ __launch_bounds__(256) void bn_apply_f32(
    const float* __restrict__ t, const float* __restrict__ scale,
    const float* __restrict__ shift, float* __restrict__ out, int ncols)
{
    size_t i4 = (size_t)blockIdx.x * 256 + threadIdx.x;
    int col0 = (int)((i4 * 4) % ncols);
    float4 v = ((const float4*)t)[i4];
    float4 o;
    o.x = fmaxf(v.x * scale[col0 + 0] + shift[col0 + 0], 0.f);
    o.y = fmaxf(v.y * scale[col0 + 1] + shift[col0 + 1], 0.f);
    o.z = fmaxf(v.z * scale[col0 + 2] + shift[col0 + 2], 0.f);
    o.w = fmaxf(v.w * scale[col0 + 3] + shift[col0 + 3], 0.f);
    ((float4*)out)[i4] = o;
}

// ---------------------------------------------------------------------------
extern "C" void kernel_launch(void* const* d_in, const int* in_sizes, int n_in,
                              void* d_out, int out_size, void* d_ws, size_t ws_size,
                              hipStream_t stream)
{
    const float* selfv = (const float*)d_in[0];   // [32,256,1024]
    const float* nbv   = (const float*)d_in[1];   // [32,256,8,2048]
    const float* mask  = (const float*)d_in[2];   // [32,256,8,1]
    const float* W_agg = (const float*)d_in[3];   // [3072,1024]
    const float* b_agg = (const float*)d_in[4];   // [1024]
    const float* W1    = (const float*)d_in[5];   // [1024,2048]
    const float* b1    = (const float*)d_in[6];   // [2048]
    const float* g1    = (const float*)d_in[7];
    const float* be1   = (const float*)d_in[8];
    const float* W2    = (const float*)d_in[9];   // [2048,1024]
    const float* b2    = (const float*)d_in[10];
    const float* g2    = (const float*)d_in[11];
    const float* be2   = (const float*)d_in[12];

    char* ws = (char*)d_ws;
    const size_t MiB = 1ull << 20;
    // layout (t1b aliases dead xb region; xb dead after GEMM1):
    __hip_bfloat16* h    = (__hip_bfloat16*)(ws + 0);          // [8192,1024] bf16, 16 MiB
    __hip_bfloat16* xb   = (__hip_bfloat16*)(ws + 16 * MiB);   // [8192,3072] bf16, 48 MiB
    __hip_bfloat16* t1b  = (__hip_bfloat16*)(ws + 16 * MiB);   // [8192,2048] bf16, 32 MiB
    __hip_bfloat16* h1   = (__hip_bfloat16*)(ws + 80 * MiB);   // [8192,2048] bf16, 32 MiB
    __hip_bfloat16* WaggT= (__hip_bfloat16*)(ws + 112 * MiB);  // [1024,3072] bf16, 6 MiB
    __hip_bfloat16* W1T  = (__hip_bfloat16*)(ws + 118 * MiB);  // [2048,1024] bf16, 4 MiB
    __hip_bfloat16* W2T  = (__hip_bfloat16*)(ws + 122 * MiB);  // [1024,2048] bf16, 4 MiB
    float* pS     = (float*)(ws + 126 * MiB);                   // [64,2048] partials
    float* pS2    = (float*)(ws + 126 * MiB + 512 * 1024);
    float* scale1 = (float*)(ws + 127 * MiB);
    float* shift1 = scale1 + 2048;
    float* scale2 = shift1 + 2048;
    float* shift2 = scale2 + 1024;

    // weight transposes (f32 -> bf16, K-major)
    wtrans<<<dim3(1024 / 32, 3072 / 32), 256, 0, stream>>>(W_agg, WaggT, 3072, 1024);
    wtrans<<<dim3(2048 / 32, 1024 / 32), 256, 0, stream>>>(W1, W1T, 1024, 2048);
    wtrans<<<dim3(1024 / 32, 2048 / 32), 256, 0, stream>>>(W2, W2T, 2048, 1024);

    // stage 1: masked mean + concat + bf16 cast
    build_x<<<ROWS, 256, 0, stream>>>(selfv, nbv, mask, xb);

    // GEMM1: h = x @ W_agg + b_agg   (bf16 out, no stats)
    gemm_bt<1, 0><<<(ROWS / 128) * (OUTC / 128), 256, 0, stream>>>(
        (const short*)xb, (const short*)WaggT, b_agg, h, nullptr, nullptr,
        ROWS, OUTC, XCOLS);

    // GEMM2: t1b = h @ W1 + b1   (bf16 out + BN1 partials from f32 accumulators)
    gemm_bt<1, 1><<<(ROWS / 128) * (HIDC / 128), 256, 0, stream>>>(
        (const short*)h, (const short*)W1T, b1, t1b, pS, pS2, ROWS, HIDC, OUTC);

    // BN1 reduce + apply + ReLU -> h1 (bf16)
    bn_stats2<<<HIDC / 256, 256, 0, stream>>>(pS, pS2, g1, be1, scale1, shift1, HIDC);
    bn_apply_b2b<<<(ROWS * HIDC) / 2048, 256, 0, stream>>>(
        (const short*)t1b, scale1, shift1, (short*)h1, HIDC);

    // GEMM3: d_out = h1 @ W2 + b2  (f32 out + BN2 partials)
    gemm_bt<0, 1><<<(ROWS / 128) * (OUTC / 128), 256, 0, stream>>>(
        (const short*)h1, (const short*)W2T, b2, d_out, pS, pS2, ROWS, OUTC, HIDC);

    // BN2 reduce + apply + ReLU in-place on d_out
    bn_stats2<<<OUTC / 256, 256, 0, stream>>>(pS, pS2, g2, be2, scale2, shift2, OUTC);
    bn_apply_f32<<<(ROWS * OUTC) / 1024, 256, 0, stream>>>(
        (const float*)d_out, scale2, shift2, (float*)d_out, OUTC);
}

// Round 5
// 419.522 us; speedup vs baseline: 1.0939x; 1.0939x over previous
//
#include <hip/hip_runtime.h>
#include <hip/hip_bf16.h>

// Problem constants (B=32, N=256, K=8, D=1024, OUT=1024, HID=2048)
#define ROWS   8192      // B*N
#define DIM    1024      // D
#define XCOLS  3072      // 3*D
#define OUTC   1024
#define HIDC   2048
#define EPS    1e-5f

typedef __attribute__((ext_vector_type(8))) short bf16x8;   // 8 bf16 (4 VGPRs)
typedef __attribute__((ext_vector_type(4))) float f32x4;

#define GLOBAL_AS __attribute__((address_space(1)))
#define LDS_AS    __attribute__((address_space(3)))

__device__ __forceinline__ void gll16(const void* g, void* l) {
    // async global->LDS, 16B per lane; LDS dest = wave-uniform base + lane*16
    __builtin_amdgcn_global_load_lds((const GLOBAL_AS void*)g, (LDS_AS void*)l, 16, 0, 0);
}

__device__ __forceinline__ short f2b(float f) {
    __hip_bfloat16 h = __float2bfloat16(f);
    return *reinterpret_cast<short*>(&h);
}
__device__ __forceinline__ float b2f(short s) {
    unsigned u = ((unsigned)(unsigned short)s) << 16;
    return __uint_as_float(u);
}

// ---------------------------------------------------------------------------
// Stage 1: x[r, 0:1024] = self[r, :]; x[r, 1024:3072] = mean_k(nb[r,k,:]*mask[r,k])
// ---------------------------------------------------------------------------
__global__ __launch_bounds__(256) void build_x(
    const float* __restrict__ selfv, const float* __restrict__ nb,
    const float* __restrict__ mask, __hip_bfloat16* __restrict__ xb)
{
    int r = blockIdx.x;
    int tid = threadIdx.x;
    __shared__ float ms[8];
    if (tid < 8) ms[tid] = mask[r * 8 + tid];
    __syncthreads();

    __hip_bfloat16* xr = xb + (size_t)r * XCOLS;

    // self part: 1024 floats = 256 float4, one per thread
    {
        float4 v = ((const float4*)(selfv + (size_t)r * DIM))[tid];
        short4 o;
        o.x = f2b(v.x); o.y = f2b(v.y); o.z = f2b(v.z); o.w = f2b(v.w);
        *(short4*)&xr[tid * 4] = o;
    }

    // entity part: 2048 cols, masked mean over K=8
    const float4* nbase = (const float4*)(nb + (size_t)r * 8 * 2048);
#pragma unroll
    for (int half = 0; half < 2; ++half) {
        int c4 = half * 256 + tid;            // float4 index in [0,512)
        float4 acc = make_float4(0.f, 0.f, 0.f, 0.f);
#pragma unroll
        for (int k = 0; k < 8; ++k) {
            float4 t = nbase[k * 512 + c4];
            float m = ms[k];
            acc.x += t.x * m; acc.y += t.y * m; acc.z += t.z * m; acc.w += t.w * m;
        }
        short4 o;
        o.x = f2b(acc.x * 0.125f); o.y = f2b(acc.y * 0.125f);
        o.z = f2b(acc.z * 0.125f); o.w = f2b(acc.w * 0.125f);
        *(short4*)&xr[1024 + c4 * 4] = o;
    }
}

// ---------------------------------------------------------------------------
// Weight transpose + bf16 cast: W[K][N] f32 -> Wt[N][K] bf16
// ---------------------------------------------------------------------------
__global__ __launch_bounds__(256) void wtrans(
    const float* __restrict__ W, __hip_bfloat16* __restrict__ Wt, int K, int N)
{
    __shared__ float t[32][33];
    int n0 = blockIdx.x << 5, k0 = blockIdx.y << 5;
    int tx = threadIdx.x & 31, ty = threadIdx.x >> 5;   // 32 x 8
#pragma unroll
    for (int i = 0; i < 4; ++i)
        t[ty + i * 8][tx] = W[(size_t)(k0 + ty + i * 8) * N + n0 + tx];
    __syncthreads();
#pragma unroll
    for (int i = 0; i < 4; ++i) {
        int n = ty + i * 8;
        Wt[(size_t)(n0 + n) * K + k0 + tx] = __float2bfloat16(t[tx][n]);
    }
}

// ---------------------------------------------------------------------------
// GEMM: C[M,N] = A[M,K] @ Bt[N,K]^T + bias   (bf16 in, f32 acc)
// 128x128 tile, BK=32, 4 waves (2x2), 16x16x32 MFMA.
// 3-buffer deep pipeline with COUNTED vmcnt (T4): tiles i..i+2 in flight;
// per iter: vmcnt(8) [oldest tile done] -> s_barrier -> ds_read+MFMA
// (setprio, T5) -> s_barrier -> stage tile i+3 into the freed buffer.
// vmcnt never drains to 0 in the main loop (tail peeled at 4 then 0).
// OUT_BF16: 1 -> bf16 C, 0 -> f32 C.
// STATS:    1 -> per-block-row column partials (sum, sumsq) incl. bias
//                into pS/pS2[bm * N + col]  (deterministic, for BatchNorm)
// ---------------------------------------------------------------------------
template <int OUT_BF16, int STATS>
__global__ __launch_bounds__(256) void gemm_bt(
    const short* __restrict__ A, const short* __restrict__ Bt,
    const float* __restrict__ bias, void* __restrict__ Cout,
    float* __restrict__ pS, float* __restrict__ pS2,
    int M, int N, int K)
{
    __shared__ short As[3][128 * 32];   // 3 x 8 KB
    __shared__ short Bs[3][128 * 32];   // 3 x 8 KB   (48 KB total)

    int tid = threadIdx.x;
    int lane = tid & 63;
    int w = tid >> 6;
    int wm = w >> 1, wn = w & 1;

    // XCD swizzle: contiguous chunk of blocks per XCD (T1; grid %8==0)
    int nwg = gridDim.x;
    int bid = blockIdx.x;
    int swz = (bid & 7) * (nwg >> 3) + (bid >> 3);

    int nbn = N >> 7;
    int bm = swz / nbn, bn = swz % nbn;
    int brow = bm << 7, bcol = bn << 7;

    f32x4 acc[4][4] = {};

    // staging addresses: slot s covers row s/4, col-elems (s%4)*8 of the 128x32 tile
    int s0 = tid, s1 = tid + 256;
    const short* gA0 = A + (size_t)(brow + (s0 >> 2)) * K + ((s0 & 3) << 3);
    const short* gA1 = A + (size_t)(brow + (s1 >> 2)) * K + ((s1 & 3) << 3);
    const short* gB0 = Bt + (size_t)(bcol + (s0 >> 2)) * K + ((s0 & 3) << 3);
    const short* gB1 = Bt + (size_t)(bcol + (s1 >> 2)) * K + ((s1 & 3) << 3);
    int lofs = w << 9;                 // wave's slot region (w*64 slots * 8 elems)

    int rowa = (wm << 6) + (lane & 15);
    int rowb = (wn << 6) + (lane & 15);
    int kc = (lane >> 4) << 3;

    short* asb = &As[0][0];
    short* bsb = &Bs[0][0];

#define STAGE(ab, bb, kk)                       \
    do {                                        \
        gll16(gA0 + (kk), (ab) + lofs);         \
        gll16(gA1 + (kk), (ab) + 2048 + lofs);  \
        gll16(gB0 + (kk), (bb) + lofs);         \
        gll16(gB1 + (kk), (bb) + 2048 + lofs);  \
    } while (0)

// One K-step on buffer (ab, bb). VM = vmcnt immediate (string literal).
// barrier #1 (after counted wait): tile valid for ALL waves' reads.
// barrier #2 (after compute):      all waves done reading -> safe to re-stage.
#define KSTEP(ab, bb, VM, DOSTAGE, KKN)                                    \
    do {                                                                   \
        asm volatile("s_waitcnt vmcnt(" VM ")" ::: "memory");              \
        __builtin_amdgcn_s_barrier();                                      \
        __builtin_amdgcn_sched_barrier(0);                                 \
        bf16x8 a[4], b[4];                                                 \
        _Pragma("unroll")                                                  \
        for (int m = 0; m < 4; ++m)                                        \
            a[m] = *(const bf16x8*)&(ab)[((rowa + (m << 4)) << 5) + kc];   \
        _Pragma("unroll")                                                  \
        for (int n = 0; n < 4; ++n)                                        \
            b[n] = *(const bf16x8*)&(bb)[((rowb + (n << 4)) << 5) + kc];   \
        __builtin_amdgcn_s_setprio(1);                                     \
        _Pragma("unroll")                                                  \
        for (int m = 0; m < 4; ++m) {                                      \
            _Pragma("unroll")                                              \
            for (int n = 0; n < 4; ++n)                                    \
                acc[m][n] = __builtin_amdgcn_mfma_f32_16x16x32_bf16(       \
                    a[m], b[n], acc[m][n], 0, 0, 0);                       \
        }                                                                  \
        __builtin_amdgcn_s_setprio(0);                                     \
        __builtin_amdgcn_sched_barrier(0);                                 \
        __builtin_amdgcn_s_barrier();                                      \
        if (DOSTAGE) STAGE(ab, bb, KKN);                                   \
    } while (0)

    int nk = K >> 5;                   // 32 / 64 / 96 here (always >= 3)

    // prologue: 3 tiles in flight (12 loads per wave)
    STAGE(asb,        bsb,        0);
    STAGE(asb + 4096, bsb + 4096, 32);
    STAGE(asb + 8192, bsb + 8192, 64);

    int p = 0;
    for (int i = 0; i < nk - 2; ++i) {
        short* ab = asb + (p << 12);
        short* bb = bsb + (p << 12);
        KSTEP(ab, bb, "8", (i + 3 < nk), ((i + 3) << 5));
        p = (p == 2) ? 0 : p + 1;
    }
    {   // tail: tiles nk-2 (wait to 4) and nk-1 (wait to 0)
        short* ab = asb + (p << 12);
        short* bb = bsb + (p << 12);
        KSTEP(ab, bb, "4", 0, 0);
        p = (p == 2) ? 0 : p + 1;
        ab = asb + (p << 12);
        bb = bsb + (p << 12);
        KSTEP(ab, bb, "0", 0, 0);
    }
#undef KSTEP
#undef STAGE

    // epilogue: C/D layout col=lane&15, row=(lane>>4)*4+reg
    int crow0 = brow + (wm << 6) + ((lane >> 4) << 2);
    int ccol0 = bcol + (wn << 6) + (lane & 15);
    float cs[4] = {0.f, 0.f, 0.f, 0.f}, cs2[4] = {0.f, 0.f, 0.f, 0.f};
#pragma unroll
    for (int m = 0; m < 4; ++m) {
#pragma unroll
        for (int n = 0; n < 4; ++n) {
            int col = ccol0 + n * 16;
            float bv = bias[col];
#pragma unroll
            for (int r = 0; r < 4; ++r) {
                int row = crow0 + m * 16 + r;
                float v = acc[m][n][r] + bv;
                if (OUT_BF16) {
                    ((__hip_bfloat16*)Cout)[(size_t)row * N + col] = __float2bfloat16(v);
                } else {
                    ((float*)Cout)[(size_t)row * N + col] = v;
                }
                if (STATS) { cs[n] += v; cs2[n] += v * v; }
            }
        }
    }

    if (STATS) {
        // reduce over lane-groups (bits 4,5 = row-subgroup axis) then across wm waves
        float* sP = (float*)&As[0][0];   // reuse LDS (all reads fenced by loop barrier)
#pragma unroll
        for (int n = 0; n < 4; ++n) {
            float s = cs[n], s2 = cs2[n];
            s  += __shfl_xor(s, 16);  s  += __shfl_xor(s, 32);
            s2 += __shfl_xor(s2, 16); s2 += __shfl_xor(s2, 32);
            if ((lane >> 4) == 0) {
                int c = (wn << 6) + (n << 4) + (lane & 15);
                sP[wm * 128 + c] = s;
                sP[256 + wm * 128 + c] = s2;
            }
        }
        __syncthreads();
        if (tid < 128) {
            float s = sP[tid] + sP[128 + tid];
            float s2 = sP[256 + tid] + sP[384 + tid];
            pS [(size_t)bm * N + bcol + tid] = s;
            pS2[(size_t)bm * N + bcol + tid] = s2;
        }
    }
}

// ---------------------------------------------------------------------------
// BN stats reduce: 64 row-chunk partials -> per-column scale/shift
// ---------------------------------------------------------------------------
__global__ __launch_bounds__(256) void bn_stats2(
    const float* __restrict__ pS, const float* __restrict__ pS2,
    const float* __restrict__ g, const float* __restrict__ be,
    float* __restrict__ scale, float* __restrict__ shift, int ncols)
{
    int col = blockIdx.x * 256 + threadIdx.x;
    float s = 0.f, s2 = 0.f;
#pragma unroll
    for (int j = 0; j < 64; ++j) {
        s += pS[j * ncols + col];
        s2 += pS2[j * ncols + col];
    }
    float mu = s * (1.f / 8192.f);
    float var = s2 * (1.f / 8192.f) - mu * mu;
    float rs = rsqrtf(var + EPS);
    float sc = g[col] * rs;
    scale[col] = sc;
    shift[col] = be[col] - mu * sc;
}

// BN apply + ReLU, bf16 in -> bf16 out (hidden activation)
__global__ __launch_bounds__(256) void bn_apply_b2b(
    const short* __restrict__ t, const float* __restrict__ scale,
    const float* __restrict__ shift, short* __restrict__ out, int ncols)
{
    size_t i8 = (size_t)blockIdx.x * 256 + threadIdx.x;
    int col0 = (int)((i8 * 8) % ncols);
    bf16x8 v = ((const bf16x8*)t)[i8];
    bf16x8 o;
#pragma unroll
    for (int j = 0; j < 8; ++j) {
        float f = fmaxf(b2f(v[j]) * scale[col0 + j] + shift[col0 + j], 0.f);
        o[j] = f2b(f);
    }
    ((bf16x8*)out)[i8] = o;
}

// BN apply + ReLU, f32 in -> f32 out (final, in-place on d_out)
__global__ __launch_bounds__(256) void bn_apply_f32(
    const float* __restrict__ t, const float* __restrict__ scale,
    const float* __restrict__ shift, float* __restrict__ out, int ncols)
{
    size_t i4 = (size_t)blockIdx.x * 256 + threadIdx.x;
    int col0 = (int)((i4 * 4) % ncols);
    float4 v = ((const float4*)t)[i4];
    float4 o;
    o.x = fmaxf(v.x * scale[col0 + 0] + shift[col0 + 0], 0.f);
    o.y = fmaxf(v.y * scale[col0 + 1] + shift[col0 + 1], 0.f);
    o.z = fmaxf(v.z * scale[col0 + 2] + shift[col0 + 2], 0.f);
    o.w = fmaxf(v.w * scale[col0 + 3] + shift[col0 + 3], 0.f);
    ((float4*)out)[i4] = o;
}

// ---------------------------------------------------------------------------
extern "C" void kernel_launch(void* const* d_in, const int* in_sizes, int n_in,
                              void* d_out, int out_size, void* d_ws, size_t ws_size,
                              hipStream_t stream)
{
    const float* selfv = (const float*)d_in[0];   // [32,256,1024]
    const float* nbv   = (const float*)d_in[1];   // [32,256,8,2048]
    const float* mask  = (const float*)d_in[2];   // [32,256,8,1]
    const float* W_agg = (const float*)d_in[3];   // [3072,1024]
    const float* b_agg = (const float*)d_in[4];   // [1024]
    const float* W1    = (const float*)d_in[5];   // [1024,2048]
    const float* b1    = (const float*)d_in[6];   // [2048]
    const float* g1    = (const float*)d_in[7];
    const float* be1   = (const float*)d_in[8];
    const float* W2    = (const float*)d_in[9];   // [2048,1024]
    const float* b2    = (const float*)d_in[10];
    const float* g2    = (const float*)d_in[11];
    const float* be2   = (const float*)d_in[12];

    char* ws = (char*)d_ws;
    const size_t MiB = 1ull << 20;
    // layout (t1b aliases dead xb region; xb dead after GEMM1):
    __hip_bfloat16* h    = (__hip_bfloat16*)(ws + 0);          // [8192,1024] bf16, 16 MiB
    __hip_bfloat16* xb   = (__hip_bfloat16*)(ws + 16 * MiB);   // [8192,3072] bf16, 48 MiB
    __hip_bfloat16* t1b  = (__hip_bfloat16*)(ws + 16 * MiB);   // [8192,2048] bf16, 32 MiB
    __hip_bfloat16* h1   = (__hip_bfloat16*)(ws + 80 * MiB);   // [8192,2048] bf16, 32 MiB
    __hip_bfloat16* WaggT= (__hip_bfloat16*)(ws + 112 * MiB);  // [1024,3072] bf16, 6 MiB
    __hip_bfloat16* W1T  = (__hip_bfloat16*)(ws + 118 * MiB);  // [2048,1024] bf16, 4 MiB
    __hip_bfloat16* W2T  = (__hip_bfloat16*)(ws + 122 * MiB);  // [1024,2048] bf16, 4 MiB
    float* pS     = (float*)(ws + 126 * MiB);                   // [64,2048] partials
    float* pS2    = (float*)(ws + 126 * MiB + 512 * 1024);
    float* scale1 = (float*)(ws + 127 * MiB);
    float* shift1 = scale1 + 2048;
    float* scale2 = shift1 + 2048;
    float* shift2 = scale2 + 1024;

    // weight transposes (f32 -> bf16, K-major)
    wtrans<<<dim3(1024 / 32, 3072 / 32), 256, 0, stream>>>(W_agg, WaggT, 3072, 1024);
    wtrans<<<dim3(2048 / 32, 1024 / 32), 256, 0, stream>>>(W1, W1T, 1024, 2048);
    wtrans<<<dim3(1024 / 32, 2048 / 32), 256, 0, stream>>>(W2, W2T, 2048, 1024);

    // stage 1: masked mean + concat + bf16 cast
    build_x<<<ROWS, 256, 0, stream>>>(selfv, nbv, mask, xb);

    // GEMM1: h = x @ W_agg + b_agg   (bf16 out, no stats)
    gemm_bt<1, 0><<<(ROWS / 128) * (OUTC / 128), 256, 0, stream>>>(
        (const short*)xb, (const short*)WaggT, b_agg, h, nullptr, nullptr,
        ROWS, OUTC, XCOLS);

    // GEMM2: t1b = h @ W1 + b1   (bf16 out + BN1 partials from f32 accumulators)
    gemm_bt<1, 1><<<(ROWS / 128) * (HIDC / 128), 256, 0, stream>>>(
        (const short*)h, (const short*)W1T, b1, t1b, pS, pS2, ROWS, HIDC, OUTC);

    // BN1 reduce + apply + ReLU -> h1 (bf16)
    bn_stats2<<<HIDC / 256, 256, 0, stream>>>(pS, pS2, g1, be1, scale1, shift1, HIDC);
    bn_apply_b2b<<<(ROWS * HIDC) / 2048, 256, 0, stream>>>(
        (const short*)t1b, scale1, shift1, (short*)h1, HIDC);

    // GEMM3: d_out = h1 @ W2 + b2  (f32 out + BN2 partials)
    gemm_bt<0, 1><<<(ROWS / 128) * (OUTC / 128), 256, 0, stream>>>(
        (const short*)h1, (const short*)W2T, b2, d_out, pS, pS2, ROWS, OUTC, HIDC);

    // BN2 reduce + apply + ReLU in-place on d_out
    bn_stats2<<<OUTC / 256, 256, 0, stream>>>(pS, pS2, g2, be2, scale2, shift2, OUTC);
    bn_apply_f32<<<(ROWS * OUTC) / 1024, 256, 0, stream>>>(
        (const float*)d_out, scale2, shift2, (float*)d_out, OUTC);
}